// Round 3
// baseline (2089.033 us; speedup 1.0000x reference)
//
// MoM block (adaLN + top-2 MoE of token/channel mixers + MLP) on MI355X.
// Round 5: occupancy attack. Counters showed k_gemm2 at 1 block/CU (Occ 8.5%,
// MfmaUtil 12%, HBM 10%) -> latency-bound with zero wave overlap. Split its
// work by slot AND K-half (grid 16 x 2C x 2 = 1024 blocks, 3-4/CU), partials
// combined via unsafeAtomicAdd into x1 (pre-initialized to x by k_copy).
// k_mlp2 gets the same split-K x2 treatment. XCD swizzle + 3-stage pipelined
// gemm_tile kept from round 4 (FETCH_SIZE halved and stays).
//
// Fixed ws layout (bytes):
//   [0, 71.3M)   bf16 MoE weights: tmw1T, tmw2T, cmw1T, cmw2T
//   [71.3M, ..)  csilu(0.26M), h(33.5M), hT(33.5M)  [hT reused for mlp w1T/w2T]
//   [138.7M, 142.2M) fp32: modp, rin, probs, tw, ti, top1, lns
//   [142.2M, ws_size) tail: adaT (12.6M) then hid/mhid chunks

#include <hip/hip_runtime.h>
#include <stdint.h>

typedef unsigned short u16;
typedef __attribute__((ext_vector_type(8))) __bf16 bf16x8;
typedef __attribute__((ext_vector_type(4))) float f32x4;

#define DEV static __device__ __forceinline__

#define VMW8 asm volatile("s_waitcnt vmcnt(8)" ::: "memory")
#define VMW4 asm volatile("s_waitcnt vmcnt(4)" ::: "memory")
#define VMW0 asm volatile("s_waitcnt vmcnt(0)" ::: "memory")
#define LGK0 asm volatile("s_waitcnt lgkmcnt(0)" ::: "memory")

DEV u16 f2b(float f) {            // fp32 -> bf16 (RNE)
  uint32_t u = __builtin_bit_cast(uint32_t, f);
  u += 0x7fffu + ((u >> 16) & 1u);
  return (u16)(u >> 16);
}
DEV float gelu_f(float x) {       // tanh-approx gelu (jax approximate=True)
  return 0.5f * x * (1.0f + tanhf(0.7978845608028654f * (x + 0.044715f * x * x * x)));
}
DEV void async_cp16(const void* g, void* l) {
  __builtin_amdgcn_global_load_lds(
      (const __attribute__((address_space(1))) unsigned int*)g,
      (__attribute__((address_space(3))) unsigned int*)l, 16, 0, 0);
}

// XCD-chunked swizzle over the linearized 3D grid: contiguous work ranges land
// on one XCD (dispatch round-robins linear id % 8). Requires nwg % 8 == 0.
DEV int xcd_work3(void) {
  int nwg = gridDim.x * gridDim.y * gridDim.z;
  int hid = blockIdx.x + gridDim.x * (blockIdx.y + gridDim.y * blockIdx.z);
  int cpx = nwg >> 3;
  return (hid & 7) * cpx + (hid >> 3);
}

// ---------------- NT bf16 GEMM tile: C(128x128) += A(128xK) * B(128xK)^T ----
// 3-stage pipeline: loads for K-step t+2 issued while computing step t.
// Steady state keeps 8 loads (2 batches of 4) in flight across barriers.
// LDS: As/Bs are 3 x 4096 u16 stage buffers (24 KB each, 48 KB total).
DEV void gemm_tile(const u16* __restrict__ A, int lda,
                   const u16* __restrict__ B, int ldb, int K,
                   u16* As, u16* Bs, f32x4 acc[4][4]) {
  const int tid = threadIdx.x;
  const int w = tid >> 6;
  const int L = tid & 63;
  const int sr = L >> 2;          // row within 16-row staging segment
  const int sk = (L & 3) * 8;     // k-element offset (16B chunks)
  const int fm = L & 15;          // fragment row
  const int fk = (L >> 4) * 8;    // fragment k offset
  const u16* ga0 = A + (size_t)(w * 32 + sr) * lda + sk;
  const u16* ga1 = ga0 + 16 * (size_t)lda;
  const u16* gb0 = B + (size_t)(w * 32 + sr) * ldb + sk;
  const u16* gb1 = gb0 + 16 * (size_t)ldb;
  const int lofs = w * 1024 + L * 8;   // lane slot within a stage (16B/lane)
  const int nst = K >> 5;              // K-steps (K multiple of 32, >= 512 here)

  VMW0;                 // stale caller vmem must not count toward our budget
  __syncthreads();      // LDS reuse guard vs prior gemm_tile call / phase

  // prologue: stage K-tiles 0,1 into stages 0,1
  {
    u16* la = As + lofs; u16* lb = Bs + lofs;
    async_cp16(ga0, la); async_cp16(ga1, la + 512);
    async_cp16(gb0, lb); async_cp16(gb1, lb + 512);
    la += 4096; lb += 4096;
    async_cp16(ga0 + 32, la); async_cp16(ga1 + 32, la + 512);
    async_cp16(gb0 + 32, lb); async_cp16(gb1 + 32, lb + 512);
  }
  int s0 = 0, s1 = 4096, s2 = 8192;    // rotating stage element offsets
  for (int t = 0; t < nst; ++t) {
    if (t + 2 < nst) {                 // issue stage t+2, keep t+1/t+2 in flight
      const int kt = (t + 2) * 32;
      u16* la = As + s2 + lofs; u16* lb = Bs + s2 + lofs;
      async_cp16(ga0 + kt, la); async_cp16(ga1 + kt, la + 512);
      async_cp16(gb0 + kt, lb); async_cp16(gb1 + kt, lb + 512);
      VMW8;                            // batch t retired (per-wave)
    } else if (t + 1 < nst) {
      VMW4;                            // epilogue: only batch t+1 in flight
    } else {
      VMW0;                            // last step: drain
    }
    __builtin_amdgcn_s_barrier();      // all waves' batch-t data in LDS
    const u16* fa = As + s0 + ((w & 1) * 64 + fm) * 32 + fk;
    const u16* fb = Bs + s0 + ((w >> 1) * 64 + fm) * 32 + fk;
    bf16x8 av[4], bv[4];
#pragma unroll
    for (int i = 0; i < 4; ++i) {
      av[i] = *(const bf16x8*)(fa + i * 512);
      bv[i] = *(const bf16x8*)(fb + i * 512);
    }
#pragma unroll
    for (int i = 0; i < 4; ++i)
#pragma unroll
      for (int j = 0; j < 4; ++j)
        acc[i][j] = __builtin_amdgcn_mfma_f32_16x16x32_bf16(av[i], bv[j], acc[i][j], 0, 0, 0);
    LGK0;                              // own reads of stage s0 done
    __builtin_amdgcn_s_barrier();      // all waves done -> s0 reusable
    __builtin_amdgcn_sched_barrier(0); // pin: next STAGE must not hoist above
    const int tmp = s0; s0 = s1; s1 = s2; s2 = tmp;
  }
}

DEV void zero_acc(f32x4 acc[4][4]) {
  f32x4 z = {0.f, 0.f, 0.f, 0.f};
#pragma unroll
  for (int i = 0; i < 4; ++i)
#pragma unroll
    for (int j = 0; j < 4; ++j) acc[i][j] = z;
}

// ---------------- diagnostic: encode ws_size (MB) into d_out[0] -------------
__global__ void k_diag(float* out, float v) {
  if (threadIdx.x == 0 && blockIdx.x == 0) out[0] = v;
}

// ---------------- x1 = x (residual base for atomic accumulation) ------------
__global__ __launch_bounds__(256) void k_copy(const float* __restrict__ src, float* __restrict__ dst) {
  size_t i = (size_t)blockIdx.x * 256 + threadIdx.x;
  ((float4*)dst)[i] = ((const float4*)src)[i];
}

// ---------------- weight transpose (fp32 RxC -> bf16 CxR), batched ----------
struct TDesc { const float* src; long dstOff; int R, C, tileStart, tilesX; };
struct TArgs { TDesc d[17]; int n; };

__global__ __launch_bounds__(256) void k_transpose(TArgs a, u16* __restrict__ ws) {
  __shared__ float tl[32][33];
  int bid = blockIdx.x;
  int di = 0;
  for (int i = 1; i < a.n; ++i) di = (bid >= a.d[i].tileStart) ? i : di;
  TDesc dd = a.d[di];
  int lt = bid - dd.tileStart;
  int tx = lt % dd.tilesX, ty = lt / dd.tilesX;   // tx over C, ty over R
  int cc = threadIdx.x & 31, rr = threadIdx.x >> 5;
  const float* sp = dd.src + (size_t)(ty * 32) * dd.C + tx * 32;
#pragma unroll
  for (int i = 0; i < 4; ++i) tl[rr + 8 * i][cc] = sp[(size_t)(rr + 8 * i) * dd.C + cc];
  __syncthreads();
  u16* dp = ws + dd.dstOff + (size_t)(tx * 32) * dd.R + ty * 32;
#pragma unroll
  for (int i = 0; i < 4; ++i) dp[(size_t)(rr + 8 * i) * dd.R + cc] = f2b(tl[cc][rr + 8 * i]);
}

// ---------------- silu(c) -> bf16, padded to 128 rows (rows 64..127 = 0) ----
__global__ __launch_bounds__(256) void k_silu(const float* __restrict__ c, u16* __restrict__ cs) {
  int row = blockIdx.x, t = threadIdx.x;
  float4 v = {0.f, 0.f, 0.f, 0.f};
  if (row < 64) v = ((const float4*)(c + (size_t)row * 1024))[t];
  ushort4 o;
  o.x = f2b(v.x / (1.f + expf(-v.x)));
  o.y = f2b(v.y / (1.f + expf(-v.y)));
  o.z = f2b(v.z / (1.f + expf(-v.z)));
  o.w = f2b(v.w / (1.f + expf(-v.w)));
  ((ushort4*)(cs + (size_t)row * 1024))[t] = o;
}

// ---------------- mod = silu(c) @ w_ada + b_ada  (M=128 incl pad) -----------
__global__ __launch_bounds__(256) void k_ada(const u16* __restrict__ cs, const u16* __restrict__ wT,
                                             const float* __restrict__ bada, float* __restrict__ modp) {
  __shared__ u16 As[12288] __attribute__((aligned(16)));
  __shared__ u16 Bs[12288] __attribute__((aligned(16)));
  int tn = blockIdx.x;
  f32x4 acc[4][4]; zero_acc(acc);
  gemm_tile(cs, 1024, wT + (size_t)tn * 131072, 1024, 1024, As, Bs, acc);
  const int tid = threadIdx.x, w = tid >> 6, L = tid & 63;
  const int rb = (w & 1) * 64 + ((L >> 4) << 2), cb = (w >> 1) * 64 + (L & 15);
#pragma unroll
  for (int i = 0; i < 4; ++i)
#pragma unroll
    for (int j = 0; j < 4; ++j) {
      int col = tn * 128 + cb + j * 16;
      float bv = bada[col];
#pragma unroll
      for (int r = 0; r < 4; ++r) {
        int row = rb + i * 16 + r;
        modp[(size_t)row * 6144 + col] = acc[i][j][r] + bv;
      }
    }
}

// ---------------- LN + modulate -> bf16 h; optionally store (mu, rstd) ------
__global__ __launch_bounds__(256) void k_ln(const float* __restrict__ xin, const float* __restrict__ modp,
                                            u16* __restrict__ hout, float* __restrict__ stats,
                                            int shOff, int scOff) {
  int n = blockIdx.x, b = blockIdx.y, t = threadIdx.x;
  const float* xr = xin + ((size_t)b * 256 + n) * 1024;
  float4 v = ((const float4*)xr)[t];
  float s = v.x + v.y + v.z + v.w;
  float s2 = v.x * v.x + v.y * v.y + v.z * v.z + v.w * v.w;
#pragma unroll
  for (int o = 32; o; o >>= 1) { s += __shfl_down(s, o); s2 += __shfl_down(s2, o); }
  __shared__ float red[8];
  int wv = t >> 6, l = t & 63;
  if (l == 0) { red[wv] = s; red[4 + wv] = s2; }
  __syncthreads();
  float S = red[0] + red[1] + red[2] + red[3];
  float S2 = red[4] + red[5] + red[6] + red[7];
  float mu = S * (1.f / 1024.f);
  float var = S2 * (1.f / 1024.f) - mu * mu;
  float rstd = rsqrtf(var + 1e-6f);
  if (stats != nullptr && t == 0) { stats[b * 256 + n] = mu; stats[16384 + b * 256 + n] = rstd; }
  float4 sh = ((const float4*)(modp + b * 6144 + shOff))[t];
  float4 sc = ((const float4*)(modp + b * 6144 + scOff))[t];
  ushort4 o;
  o.x = f2b(((v.x - mu) * rstd) * (1.f + sc.x) + sh.x);
  o.y = f2b(((v.y - mu) * rstd) * (1.f + sc.y) + sh.y);
  o.z = f2b(((v.z - mu) * rstd) * (1.f + sc.z) + sh.z);
  o.w = f2b(((v.w - mu) * rstd) * (1.f + sc.w) + sh.w);
  ((ushort4*)(hout + ((size_t)b * 256 + n) * 1024))[t] = o;
}

// ---------------- h (N x D) -> hT (D x N) per sample, bf16 ------------------
__global__ __launch_bounds__(256) void k_htrans(const u16* __restrict__ h, u16* __restrict__ hT) {
  __shared__ u16 tl[32][33];
  int b = blockIdx.z, d0 = blockIdx.x * 32, n0 = blockIdx.y * 32;
  int c = threadIdx.x & 31, r = threadIdx.x >> 5;
  const u16* src = h + (size_t)b * 262144;
#pragma unroll
  for (int i = 0; i < 4; ++i) tl[r + 8 * i][c] = src[(size_t)(n0 + r + 8 * i) * 1024 + d0 + c];
  __syncthreads();
  u16* dst = hT + (size_t)b * 262144;
#pragma unroll
  for (int i = 0; i < 4; ++i) dst[(size_t)(d0 + r + 8 * i) * 256 + n0 + c] = tl[c][r + 8 * i];
}

// ---------------- r_in: fp32-exact mean_n of modulate(ln(x)) ----------------
__global__ __launch_bounds__(256) void k_rin(const float* __restrict__ x, const float* __restrict__ lns,
                                             const float* __restrict__ modp, float* __restrict__ rin) {
  int b = blockIdx.y, d = blockIdx.x * 256 + threadIdx.x;
  const float* xp = x + (size_t)b * 262144 + d;
  const float* mu = lns + b * 256;
  const float* rs = lns + 16384 + b * 256;
  float s = 0.f;
  for (int n = 0; n < 256; ++n) s += (xp[(size_t)n * 1024] - mu[n]) * rs[n];
  float sc = modp[b * 6144 + 1024 + d], sh = modp[b * 6144 + d];
  rin[b * 1024 + d] = (1.f + sc) * (s * (1.f / 256.f)) + sh;
}

// ---------------- router: logits, softmax, top-2, combine weights -----------
__global__ __launch_bounds__(256) void k_router(const float* __restrict__ rin, const float* __restrict__ wr,
                                                float* __restrict__ probs, float* __restrict__ tw,
                                                int* __restrict__ ti, int* __restrict__ top1) {
  __shared__ float red[256][8];
  int b = blockIdx.x, t = threadIdx.x;
  float a[8];
#pragma unroll
  for (int e = 0; e < 8; ++e) a[e] = 0.f;
  for (int d = t; d < 1024; d += 256) {
    float rv = rin[b * 1024 + d];
    const float* wp = wr + d * 8;
#pragma unroll
    for (int e = 0; e < 8; ++e) a[e] += rv * wp[e];
  }
#pragma unroll
  for (int e = 0; e < 8; ++e) red[t][e] = a[e];
  __syncthreads();
  for (int s = 128; s > 0; s >>= 1) {
    if (t < s)
#pragma unroll
      for (int e = 0; e < 8; ++e) red[t][e] += red[t + s][e];
    __syncthreads();
  }
  if (t == 0) {
    float p[8];
    float m = -1e30f;
    for (int e = 0; e < 8; ++e) m = fmaxf(m, red[0][e]);
    float sum = 0.f;
    for (int e = 0; e < 8; ++e) { p[e] = expf(red[0][e] - m); sum += p[e]; }
    float inv = 1.f / sum;
    for (int e = 0; e < 8; ++e) p[e] *= inv;
    int i1 = 0;
    for (int e = 1; e < 8; ++e) if (p[e] > p[i1]) i1 = e;   // tie -> lower idx
    int i2 = -1; float bv = -1e30f;
    for (int e = 0; e < 8; ++e) if (e != i1 && p[e] > bv) { bv = p[e]; i2 = e; }
    float ss = p[i1] + p[i2];
    ti[b * 2] = i1; ti[b * 2 + 1] = i2;
    tw[b * 2] = p[i1] / ss; tw[b * 2 + 1] = p[i2] / ss;
    top1[b] = i1;
    for (int e = 0; e < 8; ++e) probs[b * 8 + e] = p[e];
  }
}

// ---------------- aux load-balancing loss -----------------------------------
__global__ void k_aux(const float* __restrict__ probs, const int* __restrict__ top1,
                      float* __restrict__ auxout) {
  if (threadIdx.x != 0) return;
  float mp[8], fr[8];
  for (int e = 0; e < 8; ++e) { mp[e] = 0.f; fr[e] = 0.f; }
  for (int b = 0; b < 64; ++b) {
    for (int e = 0; e < 8; ++e) mp[e] += probs[b * 8 + e];
    fr[top1[b]] += 1.f;
  }
  float aux = 0.f;
  for (int e = 0; e < 8; ++e) aux += (mp[e] * (1.f / 64.f)) * (fr[e] * (1.f / 64.f));
  auxout[0] = 8.f * aux;
}

// ---------------- expert GEMM1 (chunked): hid = gelu(op @ w1 + b1) ----------
// token slot (e<4):  hid[d][ht] = gelu(hT[d,:n] . tm_w1T[ht,:n])
// channel slot:      hid[n][hc] = gelu(h[n,:d]  . cm_w1T[hc,:d])
// XCD swizzle: 64 tiles of one slot are work-contiguous -> same XCD L2.
__global__ __launch_bounds__(256) void k_gemm1(const u16* __restrict__ h, const u16* __restrict__ hT,
                                               const u16* __restrict__ tmw1T, const u16* __restrict__ cmw1T,
                                               const float* __restrict__ tm_b1, const float* __restrict__ cm_b1,
                                               const int* __restrict__ ti, u16* __restrict__ hid, int slot0) {
  __shared__ u16 As[12288] __attribute__((aligned(16)));
  __shared__ u16 Bs[12288] __attribute__((aligned(16)));
  const int wrk = xcd_work3();
  int tile = wrk & 63;                 // gridDim.x == 64
  int ly = wrk >> 6;                   // local slot index within pass
  int slot = slot0 + ly;
  int b = slot >> 1;
  int e = ti[slot];
  f32x4 acc[4][4]; zero_acc(acc);
  const int tid = threadIdx.x, w = tid >> 6, L = tid & 63;
  const int rb = (w & 1) * 64 + ((L >> 4) << 2), cb = (w >> 1) * 64 + (L & 15);
  u16* outp = hid + (size_t)ly * 1048576;
  if (e < 4) {                     // token mixer: M=1024(d) x N=1024(ht), K=256(n)
    int tm = tile >> 3, tn = tile & 7;
    gemm_tile(hT + (size_t)b * 262144 + (size_t)tm * 128 * 256, 256,
              tmw1T + (size_t)e * 262144 + (size_t)tn * 128 * 256, 256, 256, As, Bs, acc);
    const float* bias = tm_b1 + e * 1024 + tn * 128;
#pragma unroll
    for (int i = 0; i < 4; ++i)
#pragma unroll
      for (int j = 0; j < 4; ++j) {
        int col = cb + j * 16;
        float bv = bias[col];
#pragma unroll
        for (int r = 0; r < 4; ++r) {
          int row = tm * 128 + rb + i * 16 + r;
          outp[(size_t)row * 1024 + tn * 128 + col] = f2b(gelu_f(acc[i][j][r] + bv));
        }
      }
  } else {                         // channel mixer: M=256(n) x N=4096(hc), K=1024(d)
    int ec = e - 4;
    int tm = tile >> 5, tn = tile & 31;
    gemm_tile(h + (size_t)b * 262144 + (size_t)tm * 128 * 1024, 1024,
              cmw1T + (size_t)ec * 4194304 + (size_t)tn * 128 * 1024, 1024, 1024, As, Bs, acc);
    const float* bias = cm_b1 + ec * 4096 + tn * 128;
#pragma unroll
    for (int i = 0; i < 4; ++i)
#pragma unroll
      for (int j = 0; j < 4; ++j) {
        int col = cb + j * 16;
        float bv = bias[col];
#pragma unroll
        for (int r = 0; r < 4; ++r) {
          int row = tm * 128 + rb + i * 16 + r;
          outp[(size_t)row * 4096 + tn * 128 + col] = f2b(gelu_f(acc[i][j][r] + bv));
        }
      }
  }
}

// ---------------- expert GEMM2: one (slot, K-half) partial per block --------
// x1 pre-initialized to x; block atomically adds gm * w_e * (acc [+ bias]).
// grid (16, 2C, 2): x = output tile (2 tm x 8 tn), y = local slot, z = K-half.
__global__ __launch_bounds__(256) void k_gemm2(const u16* __restrict__ hid,
                                               const u16* __restrict__ tmw2T, const u16* __restrict__ cmw2T,
                                               const float* __restrict__ tm_b2, const float* __restrict__ cm_b2,
                                               const int* __restrict__ ti, const float* __restrict__ tw,
                                               const float* __restrict__ modp,
                                               float* __restrict__ x1, int slot0) {
  __shared__ u16 As[12288] __attribute__((aligned(16)));
  __shared__ u16 Bs[12288] __attribute__((aligned(16)));
  const int wrk = xcd_work3();
  int tile = wrk & 15;                 // 16 tiles: tm(2) x tn(8)
  int kh = (wrk >> 4) & 1;             // K-half
  int ly = wrk >> 5;                   // local slot within pass
  int tm = tile >> 3, tn = tile & 7;   // tm over n(256), tn over d(1024)
  int slot = slot0 + ly;
  int b = slot >> 1;
  int e = ti[slot];
  float we = tw[slot];
  f32x4 acc[4][4]; zero_acc(acc);
  const int tid = threadIdx.x, w = tid >> 6, L = tid & 63;
  const int rb = (w & 1) * 64 + ((L >> 4) << 2), cb = (w >> 1) * 64 + (L & 15);
  const u16* hidS = hid + (size_t)ly * 1048576;
  if (e < 4) {                         // token: M=n(256) K=1024 -> half 512
    gemm_tile(tmw2T + (size_t)e * 262144 + (size_t)tm * 128 * 1024 + (size_t)kh * 512, 1024,
              hidS + (size_t)tn * 128 * 1024 + (size_t)kh * 512, 1024, 512, As, Bs, acc);
  } else {                             // channel: K=4096 -> half 2048
    gemm_tile(hidS + (size_t)tm * 128 * 4096 + (size_t)kh * 2048, 4096,
              cmw2T + (size_t)(e - 4) * 4194304 + (size_t)tn * 128 * 4096 + (size_t)kh * 2048, 4096,
              2048, As, Bs, acc);
  }
  const float* gm = modp + b * 6144 + 2048;
  float* orow = x1 + (size_t)b * 262144;
#pragma unroll
  for (int i = 0; i < 4; ++i)
#pragma unroll
    for (int j = 0; j < 4; ++j)
#pragma unroll
      for (int r = 0; r < 4; ++r) {
        int rowg = tm * 128 + rb + i * 16 + r;
        int colg = tn * 128 + cb + j * 16;
        float bv = (kh == 0)
                       ? ((e < 4) ? tm_b2[e * 256 + rowg] : cm_b2[(e - 4) * 1024 + colg])
                       : 0.f;
        float term = gm[colg] * (we * (acc[i][j][r] + bv));
        unsafeAtomicAdd(&orow[(size_t)rowg * 1024 + colg], term);
      }
}

// ---------------- MLP GEMM1 (row-chunked): mhid = gelu(h2 @ w1 + b1) --------
// XCD swizzle: contiguous work = tn fastest -> same-XCD blocks share A rows.
__global__ __launch_bounds__(256) void k_mlp1(const u16* __restrict__ h2, const u16* __restrict__ w1T,
                                              const float* __restrict__ b1, u16* __restrict__ mhid, int r0) {
  __shared__ u16 As[12288] __attribute__((aligned(16)));
  __shared__ u16 Bs[12288] __attribute__((aligned(16)));
  const int wrk = xcd_work3();
  int tn = wrk & 31, tm = wrk >> 5;       // gridDim.x == 32
  f32x4 acc[4][4]; zero_acc(acc);
  gemm_tile(h2 + (size_t)(r0 + tm * 128) * 1024, 1024, w1T + (size_t)tn * 131072, 1024, 1024, As, Bs, acc);
  const int tid = threadIdx.x, w = tid >> 6, L = tid & 63;
  const int rb = (w & 1) * 64 + ((L >> 4) << 2), cb = (w >> 1) * 64 + (L & 15);
  const float* bias = b1 + tn * 128;
#pragma unroll
  for (int i = 0; i < 4; ++i)
#pragma unroll
    for (int j = 0; j < 4; ++j) {
      int col = cb + j * 16;
      float bv = bias[col];
#pragma unroll
      for (int r = 0; r < 4; ++r) {
        int row = tm * 128 + rb + i * 16 + r;   // local row in chunk
        mhid[(size_t)row * 4096 + tn * 128 + col] = f2b(gelu_f(acc[i][j][r] + bv));
      }
    }
}

// ---------------- MLP GEMM2 + final residual (split-K x2, atomic) -----------
// xio already holds x1; each (tn, kh, tm) block adds modp * (acc [+ bias]).
__global__ __launch_bounds__(256) void k_mlp2(const u16* __restrict__ mhid, const u16* __restrict__ w2T,
                                              const float* __restrict__ b2, const float* __restrict__ modp,
                                              float* __restrict__ xio, int r0) {
  __shared__ u16 As[12288] __attribute__((aligned(16)));
  __shared__ u16 Bs[12288] __attribute__((aligned(16)));
  const int wrk = xcd_work3();
  int tn = wrk & 7, kh = (wrk >> 3) & 1, tm = wrk >> 4;   // gridDim.x == 16
  f32x4 acc[4][4]; zero_acc(acc);
  gemm_tile(mhid + (size_t)tm * 524288 + (size_t)kh * 2048, 4096,
            w2T + (size_t)tn * 524288 + (size_t)kh * 2048, 4096, 2048, As, Bs, acc);
  const int tid = threadIdx.x, w = tid >> 6, L = tid & 63;
  const int rb = (w & 1) * 64 + ((L >> 4) << 2), cb = (w >> 1) * 64 + (L & 15);
#pragma unroll
  for (int i = 0; i < 4; ++i)
#pragma unroll
    for (int j = 0; j < 4; ++j) {
      int col = tn * 128 + cb + j * 16;
      float bv = (kh == 0) ? b2[col] : 0.f;
#pragma unroll
      for (int r = 0; r < 4; ++r) {
        int gr = r0 + tm * 128 + rb + i * 16 + r;   // global flat row [0,16384)
        int bq = gr >> 8;
        float term = modp[bq * 6144 + 5120 + col] * (acc[i][j][r] + bv);
        unsafeAtomicAdd(&xio[(size_t)gr * 1024 + col], term);
      }
    }
}

// ---------------- host ------------------------------------------------------
extern "C" void kernel_launch(void* const* d_in, const int* in_sizes, int n_in,
                              void* d_out, int out_size, void* d_ws, size_t ws_size,
                              hipStream_t stream) {
  (void)in_sizes; (void)n_in; (void)out_size;
  const float* x        = (const float*)d_in[0];
  const float* c        = (const float*)d_in[1];
  const float* w_ada    = (const float*)d_in[2];
  const float* b_ada    = (const float*)d_in[3];
  const float* w_router = (const float*)d_in[4];
  const float* tm_w1    = (const float*)d_in[5];
  const float* tm_b1    = (const float*)d_in[6];
  const float* tm_w2    = (const float*)d_in[7];
  const float* tm_b2    = (const float*)d_in[8];
  const float* cm_w1    = (const float*)d_in[9];
  const float* cm_b1    = (const float*)d_in[10];
  const float* cm_w2    = (const float*)d_in[11];
  const float* cm_b2    = (const float*)d_in[12];
  const float* mlp_w1   = (const float*)d_in[13];
  const float* mlp_b1   = (const float*)d_in[14];
  const float* mlp_w2   = (const float*)d_in[15];
  const float* mlp_b2   = (const float*)d_in[16];

  // ---- fixed layout (element offsets for bf16 region) ----
  u16* ws16 = (u16*)d_ws;
  char* wsb = (char*)d_ws;
  u16* tmw1T = ws16;                       // 1,048,576 elts
  u16* tmw2T = ws16 + 1048576L;            // 1,048,576
  u16* cmw1T = ws16 + 2097152L;            // 16,777,216
  u16* cmw2T = ws16 + 18874368L;           // 16,777,216
  u16* csilu = ws16 + 35651584L;           // 131,072
  u16* h     = ws16 + 35782656L;           // 16,777,216 (reused as h2)
  u16* hT    = ws16 + 52559872L;           // 16,777,216 (reused: mlp w1T/w2T)
  u16* mw1T  = ws16 + 52559872L;           // 4,194,304 (after MoE)
  u16* mw2T  = ws16 + 56754176L;           // 4,194,304
  float* modp  = (float*)(wsb + 138674176L);   // 128 x 6144 fp32
  float* rin   = (float*)(wsb + 141819904L);   // 64 x 1024
  float* probs = (float*)(wsb + 142082048L);   // 64 x 8
  float* twp   = (float*)(wsb + 142084096L);   // 128
  int*   tip   = (int*)(wsb + 142084608L);     // 128
  int*   top1p = (int*)(wsb + 142085120L);     // 64
  float* lns   = (float*)(wsb + 142085376L);   // 2 x 16384
  const size_t FIXED_END = 142216448ULL;       // tail start (16B aligned)
  u16* tailb = ws16 + FIXED_END / 2;           // adaT, then hid/mhid chunks
  float* x1 = (float*)d_out;                   // x1 lives in the output buffer

  if (ws_size < FIXED_END + 12582912ULL) {     // can't even fit adaT
    k_diag<<<1, 64, 0, stream>>>((float*)d_out, (float)(ws_size >> 20));
    return;
  }
  size_t tail = ws_size - FIXED_END;
  int C = 64;                                  // samples per MoE pass
  while ((size_t)C * 4194304ULL > tail) C >>= 1;
  int R = 16384;                               // rows per MLP pass
  while ((size_t)R * 8192ULL > tail) R >>= 1;

  // ---- T1: adaT (tail) + MoE weights ----
  TArgs t1; int k = 0, start = 0;
#define ADD_T(TA, SRC, DST, RR, CC)                                       \
  do {                                                                    \
    TA.d[k].src = (SRC); TA.d[k].dstOff = (DST);                          \
    TA.d[k].R = (RR); TA.d[k].C = (CC);                                   \
    TA.d[k].tileStart = start; TA.d[k].tilesX = (CC) / 32;                \
    start += ((RR) / 32) * ((CC) / 32); ++k;                              \
  } while (0)
  ADD_T(t1, w_ada, (long)(FIXED_END / 2), 1024, 6144);
  for (int e = 0; e < 4; ++e) ADD_T(t1, tm_w1 + (long)e * 262144, 0L + (long)e * 262144, 256, 1024);
  for (int e = 0; e < 4; ++e) ADD_T(t1, tm_w2 + (long)e * 262144, 1048576L + (long)e * 262144, 1024, 256);
  for (int e = 0; e < 4; ++e) ADD_T(t1, cm_w1 + (long)e * 4194304, 2097152L + (long)e * 4194304, 1024, 4096);
  for (int e = 0; e < 4; ++e) ADD_T(t1, cm_w2 + (long)e * 4194304, 18874368L + (long)e * 4194304, 4096, 1024);
  t1.n = k;
  int t1_tiles = start;                        // 40960

  TArgs t2; k = 0; start = 0;
  ADD_T(t2, mlp_w1, 52559872L, 1024, 4096);
  ADD_T(t2, mlp_w2, 56754176L, 4096, 1024);
  t2.n = k;
  int t2_tiles = start;                        // 8192
#undef ADD_T

  k_transpose<<<dim3(t1_tiles), dim3(256), 0, stream>>>(t1, ws16);
  k_copy<<<dim3(16384), dim3(256), 0, stream>>>(x, x1);   // x1 = x (atomic base)
  k_silu<<<dim3(128), dim3(256), 0, stream>>>(c, csilu);
  k_ada<<<dim3(48), dim3(256), 0, stream>>>(csilu, tailb, b_ada, modp);
  k_ln<<<dim3(256, 64), dim3(256), 0, stream>>>(x, modp, h, lns, 0, 1024);
  k_htrans<<<dim3(32, 8, 64), dim3(256), 0, stream>>>(h, hT);
  k_rin<<<dim3(4, 64), dim3(256), 0, stream>>>(x, lns, modp, rin);
  k_router<<<dim3(64), dim3(256), 0, stream>>>(rin, w_router, probs, twp, tip, top1p);
  k_aux<<<dim3(1), dim3(64), 0, stream>>>(probs, top1p, (float*)d_out + 16777216L);
  // ---- MoE passes (hid chunk in tail; overwrites adaT, which is now dead)
  for (int b0 = 0; b0 < 64; b0 += C) {
    k_gemm1<<<dim3(64, 2 * C), dim3(256), 0, stream>>>(h, hT, tmw1T, cmw1T, tm_b1, cm_b1, tip, tailb, 2 * b0);
    k_gemm2<<<dim3(16, 2 * C, 2), dim3(256), 0, stream>>>(tailb, tmw2T, cmw2T, tm_b2, cm_b2, tip, twp, modp, x1, 2 * b0);
  }
  // ---- MLP weights into hT region (dead after last k_gemm1) ----
  k_transpose<<<dim3(t2_tiles), dim3(256), 0, stream>>>(t2, ws16);
  k_ln<<<dim3(256, 64), dim3(256), 0, stream>>>(x1, modp, h, nullptr, 3072, 4096);
  for (int r0 = 0; r0 < 16384; r0 += R) {
    k_mlp1<<<dim3(32, R / 128), dim3(256), 0, stream>>>(h, mw1T, mlp_b1, tailb, r0);
    k_mlp2<<<dim3(16, R / 128), dim3(256), 0, stream>>>(tailb, mw2T, mlp_b2, modp, x1, r0);
  }
}

// Round 5
// 1754.861 us; speedup vs baseline: 1.1904x; 1.1904x over previous
//
// MoM block (adaLN + top-2 MoE of token/channel mixers + MLP) on MI355X.
// Round 7 (= round 6 + paren fix): LDS bank-conflict swizzle + cheap gelu;
// gemm2/mlp2 in round-2 fused non-atomic forms. Evidence: VALUBusy 27.6% in
// gemm1 (tanhf epilogue) and 6.4M LDS conflict cycles/dispatch (8-way
// conflict on fragment ds_read_b128, row stride 64B = 16 banks). Swizzle:
// pre-permute per-lane GLOBAL source chunk, same XOR on fragment read
// (linear LDS dest, rule both-sides-or-neither).
//
// Fixed ws layout (bytes):
//   [0, 71.3M)   bf16 MoE weights: tmw1T, tmw2T, cmw1T, cmw2T
//   [71.3M, ..)  csilu(0.26M), h(33.5M), hT(33.5M)  [hT reused for mlp w1T/w2T]
//   [138.7M, 142.2M) fp32: modp, rin, probs, tw, ti, top1, lns
//   [142.2M, ws_size) tail: adaT (12.6M) then hid/mhid chunks

#include <hip/hip_runtime.h>
#include <stdint.h>

typedef unsigned short u16;
typedef __attribute__((ext_vector_type(8))) __bf16 bf16x8;
typedef __attribute__((ext_vector_type(4))) float f32x4;

#define DEV static __device__ __forceinline__

#define VMW8 asm volatile("s_waitcnt vmcnt(8)" ::: "memory")
#define VMW4 asm volatile("s_waitcnt vmcnt(4)" ::: "memory")
#define VMW0 asm volatile("s_waitcnt vmcnt(0)" ::: "memory")
#define LGK0 asm volatile("s_waitcnt lgkmcnt(0)" ::: "memory")

DEV u16 f2b(float f) {            // fp32 -> bf16 (RNE)
  uint32_t u = __builtin_bit_cast(uint32_t, f);
  u += 0x7fffu + ((u >> 16) & 1u);
  return (u16)(u >> 16);
}
// tanh-approx gelu in sigmoid form: 0.5x(1+tanh(z)) == x/(1+exp(-2z)).
// __expf + v_rcp_f32: ~7 VALU ops vs tanhf's libm expansion.
DEV float gelu_f(float x) {
  float z2 = x * (1.5957691216f + 0.0713548128f * x * x);  // 2*0.79788456*(x+0.044715x^3)
  float e = __expf(-z2);
  return x * __builtin_amdgcn_rcpf(1.0f + e);
}
DEV void async_cp16(const void* g, void* l) {
  __builtin_amdgcn_global_load_lds(
      (const __attribute__((address_space(1))) unsigned int*)g,
      (__attribute__((address_space(3))) unsigned int*)l, 16, 0, 0);
}

// XCD-chunked swizzle: hardware linear id -> work id so contiguous work
// ranges land on one XCD (dispatch round-robins linear id % 8 across XCDs).
// Requires total blocks % 8 == 0 (all call sites satisfy this).
DEV int xcd_work(void) {
  int nwg = gridDim.x * gridDim.y * gridDim.z;
  int hid = blockIdx.x + gridDim.x * (blockIdx.y + gridDim.y * blockIdx.z);
  int cpx = nwg >> 3;
  return (hid & 7) * cpx + (hid >> 3);
}

// ---------------- NT bf16 GEMM tile: C(128x128) += A(128xK) * B(128xK)^T ----
// 3-stage pipeline (counted vmcnt), plus bank-conflict swizzle:
// LDS stage layout is [row][4 chunks of 8 elem]; the chunk stored at slot c
// for row r is global chunk c ^ ((r>>1)&3). Staging achieves this by
// pre-swizzling the per-lane GLOBAL chunk (LDS dest stays linear, as
// global_load_lds requires); fragment reads apply the same XOR. Turns the
// 8-way bank conflict (row stride 64B = 16 banks) into a free 2-way.
DEV void gemm_tile(const u16* __restrict__ A, int lda,
                   const u16* __restrict__ B, int ldb, int K,
                   u16* As, u16* Bs, f32x4 acc[4][4]) {
  const int tid = threadIdx.x;
  const int w = tid >> 6;
  const int L = tid & 63;
  const int sr = L >> 2;          // row within 16-row staging segment
  const int sk = ((L & 3) ^ ((sr >> 1) & 3)) * 8;   // swizzled source chunk
  const int fm = L & 15;          // fragment row
  const int fk = ((L >> 4) ^ ((fm >> 1) & 3)) * 8;  // swizzled fragment chunk
  const u16* ga0 = A + (size_t)(w * 32 + sr) * lda + sk;
  const u16* ga1 = ga0 + 16 * (size_t)lda;          // +16 rows: same XOR key
  const u16* gb0 = B + (size_t)(w * 32 + sr) * ldb + sk;
  const u16* gb1 = gb0 + 16 * (size_t)ldb;
  const int lofs = w * 1024 + L * 8;   // lane slot within a stage (16B/lane)
  const int nst = K >> 5;              // K-steps (K multiple of 32, >= 256)

  VMW0;                 // stale caller vmem must not count toward our budget
  __syncthreads();      // LDS reuse guard vs prior gemm_tile call / phase

  // prologue: stage K-tiles 0,1 into stages 0,1
  {
    u16* la = As + lofs; u16* lb = Bs + lofs;
    async_cp16(ga0, la); async_cp16(ga1, la + 512);
    async_cp16(gb0, lb); async_cp16(gb1, lb + 512);
    la += 4096; lb += 4096;
    async_cp16(ga0 + 32, la); async_cp16(ga1 + 32, la + 512);
    async_cp16(gb0 + 32, lb); async_cp16(gb1 + 32, lb + 512);
  }
  int s0 = 0, s1 = 4096, s2 = 8192;    // rotating stage element offsets
  for (int t = 0; t < nst; ++t) {
    if (t + 2 < nst) {                 // issue stage t+2, keep t+1/t+2 in flight
      const int kt = (t + 2) * 32;
      u16* la = As + s2 + lofs; u16* lb = Bs + s2 + lofs;
      async_cp16(ga0 + kt, la); async_cp16(ga1 + kt, la + 512);
      async_cp16(gb0 + kt, lb); async_cp16(gb1 + kt, lb + 512);
      VMW8;                            // batch t retired (per-wave)
    } else if (t + 1 < nst) {
      VMW4;                            // epilogue: only batch t+1 in flight
    } else {
      VMW0;                            // last step: drain
    }
    __builtin_amdgcn_s_barrier();      // all waves' batch-t data in LDS
    const u16* fa = As + s0 + ((w & 1) * 64 + fm) * 32 + fk;
    const u16* fb = Bs + s0 + ((w >> 1) * 64 + fm) * 32 + fk;
    bf16x8 av[4], bv[4];
#pragma unroll
    for (int i = 0; i < 4; ++i) {      // +i*16 rows: XOR key unchanged
      av[i] = *(const bf16x8*)(fa + i * 512);
      bv[i] = *(const bf16x8*)(fb + i * 512);
    }
#pragma unroll
    for (int i = 0; i < 4; ++i)
#pragma unroll
      for (int j = 0; j < 4; ++j)
        acc[i][j] = __builtin_amdgcn_mfma_f32_16x16x32_bf16(av[i], bv[j], acc[i][j], 0, 0, 0);
    LGK0;                              // own reads of stage s0 done
    __builtin_amdgcn_s_barrier();      // all waves done -> s0 reusable
    __builtin_amdgcn_sched_barrier(0); // pin: next STAGE must not hoist above
    const int tmp = s0; s0 = s1; s1 = s2; s2 = tmp;
  }
}

DEV void zero_acc(f32x4 acc[4][4]) {
  f32x4 z = {0.f, 0.f, 0.f, 0.f};
#pragma unroll
  for (int i = 0; i < 4; ++i)
#pragma unroll
    for (int j = 0; j < 4; ++j) acc[i][j] = z;
}

// ---------------- diagnostic: encode ws_size (MB) into d_out[0] -------------
__global__ void k_diag(float* out, float v) {
  if (threadIdx.x == 0 && blockIdx.x == 0) out[0] = v;
}

// ---------------- weight transpose (fp32 RxC -> bf16 CxR), batched ----------
struct TDesc { const float* src; long dstOff; int R, C, tileStart, tilesX; };
struct TArgs { TDesc d[17]; int n; };

__global__ __launch_bounds__(256) void k_transpose(TArgs a, u16* __restrict__ ws) {
  __shared__ float tl[32][33];
  int bid = blockIdx.x;
  int di = 0;
  for (int i = 1; i < a.n; ++i) di = (bid >= a.d[i].tileStart) ? i : di;
  TDesc dd = a.d[di];
  int lt = bid - dd.tileStart;
  int tx = lt % dd.tilesX, ty = lt / dd.tilesX;   // tx over C, ty over R
  int cc = threadIdx.x & 31, rr = threadIdx.x >> 5;
  const float* sp = dd.src + (size_t)(ty * 32) * dd.C + tx * 32;
#pragma unroll
  for (int i = 0; i < 4; ++i) tl[rr + 8 * i][cc] = sp[(size_t)(rr + 8 * i) * dd.C + cc];
  __syncthreads();
  u16* dp = ws + dd.dstOff + (size_t)(tx * 32) * dd.R + ty * 32;
#pragma unroll
  for (int i = 0; i < 4; ++i) dp[(size_t)(rr + 8 * i) * dd.R + cc] = f2b(tl[cc][rr + 8 * i]);
}

// ---------------- silu(c) -> bf16, padded to 128 rows (rows 64..127 = 0) ----
__global__ __launch_bounds__(256) void k_silu(const float* __restrict__ c, u16* __restrict__ cs) {
  int row = blockIdx.x, t = threadIdx.x;
  float4 v = {0.f, 0.f, 0.f, 0.f};
  if (row < 64) v = ((const float4*)(c + (size_t)row * 1024))[t];
  ushort4 o;
  o.x = f2b(v.x / (1.f + expf(-v.x)));
  o.y = f2b(v.y / (1.f + expf(-v.y)));
  o.z = f2b(v.z / (1.f + expf(-v.z)));
  o.w = f2b(v.w / (1.f + expf(-v.w)));
  ((ushort4*)(cs + (size_t)row * 1024))[t] = o;
}

// ---------------- mod = silu(c) @ w_ada + b_ada  (M=128 incl pad) -----------
__global__ __launch_bounds__(256) void k_ada(const u16* __restrict__ cs, const u16* __restrict__ wT,
                                             const float* __restrict__ bada, float* __restrict__ modp) {
  __shared__ u16 As[12288] __attribute__((aligned(16)));
  __shared__ u16 Bs[12288] __attribute__((aligned(16)));
  int tn = blockIdx.x;
  f32x4 acc[4][4]; zero_acc(acc);
  gemm_tile(cs, 1024, wT + (size_t)tn * 131072, 1024, 1024, As, Bs, acc);
  const int tid = threadIdx.x, w = tid >> 6, L = tid & 63;
  const int rb = (w & 1) * 64 + ((L >> 4) << 2), cb = (w >> 1) * 64 + (L & 15);
#pragma unroll
  for (int i = 0; i < 4; ++i)
#pragma unroll
    for (int j = 0; j < 4; ++j) {
      int col = tn * 128 + cb + j * 16;
      float bv = bada[col];
#pragma unroll
      for (int r = 0; r < 4; ++r) {
        int row = rb + i * 16 + r;
        modp[(size_t)row * 6144 + col] = acc[i][j][r] + bv;
      }
    }
}

// ---------------- LN + modulate -> bf16 h; optionally store (mu, rstd) ------
__global__ __launch_bounds__(256) void k_ln(const float* __restrict__ xin, const float* __restrict__ modp,
                                            u16* __restrict__ hout, float* __restrict__ stats,
                                            int shOff, int scOff) {
  int n = blockIdx.x, b = blockIdx.y, t = threadIdx.x;
  const float* xr = xin + ((size_t)b * 256 + n) * 1024;
  float4 v = ((const float4*)xr)[t];
  float s = v.x + v.y + v.z + v.w;
  float s2 = v.x * v.x + v.y * v.y + v.z * v.z + v.w * v.w;
#pragma unroll
  for (int o = 32; o; o >>= 1) { s += __shfl_down(s, o); s2 += __shfl_down(s2, o); }
  __shared__ float red[8];
  int wv = t >> 6, l = t & 63;
  if (l == 0) { red[wv] = s; red[4 + wv] = s2; }
  __syncthreads();
  float S = red[0] + red[1] + red[2] + red[3];
  float S2 = red[4] + red[5] + red[6] + red[7];
  float mu = S * (1.f / 1024.f);
  float var = S2 * (1.f / 1024.f) - mu * mu;
  float rstd = rsqrtf(var + 1e-6f);
  if (stats != nullptr && t == 0) { stats[b * 256 + n] = mu; stats[16384 + b * 256 + n] = rstd; }
  float4 sh = ((const float4*)(modp + b * 6144 + shOff))[t];
  float4 sc = ((const float4*)(modp + b * 6144 + scOff))[t];
  ushort4 o;
  o.x = f2b(((v.x - mu) * rstd) * (1.f + sc.x) + sh.x);
  o.y = f2b(((v.y - mu) * rstd) * (1.f + sc.y) + sh.y);
  o.z = f2b(((v.z - mu) * rstd) * (1.f + sc.z) + sh.z);
  o.w = f2b(((v.w - mu) * rstd) * (1.f + sc.w) + sh.w);
  ((ushort4*)(hout + ((size_t)b * 256 + n) * 1024))[t] = o;
}

// ---------------- h (N x D) -> hT (D x N) per sample, bf16 ------------------
__global__ __launch_bounds__(256) void k_htrans(const u16* __restrict__ h, u16* __restrict__ hT) {
  __shared__ u16 tl[32][33];
  int b = blockIdx.z, d0 = blockIdx.x * 32, n0 = blockIdx.y * 32;
  int c = threadIdx.x & 31, r = threadIdx.x >> 5;
  const u16* src = h + (size_t)b * 262144;
#pragma unroll
  for (int i = 0; i < 4; ++i) tl[r + 8 * i][c] = src[(size_t)(n0 + r + 8 * i) * 1024 + d0 + c];
  __syncthreads();
  u16* dst = hT + (size_t)b * 262144;
#pragma unroll
  for (int i = 0; i < 4; ++i) dst[(size_t)(d0 + r + 8 * i) * 256 + n0 + c] = tl[c][r + 8 * i];
}

// ---------------- r_in: fp32-exact mean_n of modulate(ln(x)) ----------------
__global__ __launch_bounds__(256) void k_rin(const float* __restrict__ x, const float* __restrict__ lns,
                                             const float* __restrict__ modp, float* __restrict__ rin) {
  int b = blockIdx.y, d = blockIdx.x * 256 + threadIdx.x;
  const float* xp = x + (size_t)b * 262144 + d;
  const float* mu = lns + b * 256;
  const float* rs = lns + 16384 + b * 256;
  float s = 0.f;
  for (int n = 0; n < 256; ++n) s += (xp[(size_t)n * 1024] - mu[n]) * rs[n];
  float sc = modp[b * 6144 + 1024 + d], sh = modp[b * 6144 + d];
  rin[b * 1024 + d] = (1.f + sc) * (s * (1.f / 256.f)) + sh;
}

// ---------------- router: logits, softmax, top-2, combine weights -----------
__global__ __launch_bounds__(256) void k_router(const float* __restrict__ rin, const float* __restrict__ wr,
                                                float* __restrict__ probs, float* __restrict__ tw,
                                                int* __restrict__ ti, int* __restrict__ top1) {
  __shared__ float red[256][8];
  int b = blockIdx.x, t = threadIdx.x;
  float a[8];
#pragma unroll
  for (int e = 0; e < 8; ++e) a[e] = 0.f;
  for (int d = t; d < 1024; d += 256) {
    float rv = rin[b * 1024 + d];
    const float* wp = wr + d * 8;
#pragma unroll
    for (int e = 0; e < 8; ++e) a[e] += rv * wp[e];
  }
#pragma unroll
  for (int e = 0; e < 8; ++e) red[t][e] = a[e];
  __syncthreads();
  for (int s = 128; s > 0; s >>= 1) {
    if (t < s)
#pragma unroll
      for (int e = 0; e < 8; ++e) red[t][e] += red[t + s][e];
    __syncthreads();
  }
  if (t == 0) {
    float p[8];
    float m = -1e30f;
    for (int e = 0; e < 8; ++e) m = fmaxf(m, red[0][e]);
    float sum = 0.f;
    for (int e = 0; e < 8; ++e) { p[e] = expf(red[0][e] - m); sum += p[e]; }
    float inv = 1.f / sum;
    for (int e = 0; e < 8; ++e) p[e] *= inv;
    int i1 = 0;
    for (int e = 1; e < 8; ++e) if (p[e] > p[i1]) i1 = e;   // tie -> lower idx
    int i2 = -1; float bv = -1e30f;
    for (int e = 0; e < 8; ++e) if (e != i1 && p[e] > bv) { bv = p[e]; i2 = e; }
    float ss = p[i1] + p[i2];
    ti[b * 2] = i1; ti[b * 2 + 1] = i2;
    tw[b * 2] = p[i1] / ss; tw[b * 2 + 1] = p[i2] / ss;
    top1[b] = i1;
    for (int e = 0; e < 8; ++e) probs[b * 8 + e] = p[e];
  }
}

// ---------------- aux load-balancing loss -----------------------------------
__global__ void k_aux(const float* __restrict__ probs, const int* __restrict__ top1,
                      float* __restrict__ auxout) {
  if (threadIdx.x != 0) return;
  float mp[8], fr[8];
  for (int e = 0; e < 8; ++e) { mp[e] = 0.f; fr[e] = 0.f; }
  for (int b = 0; b < 64; ++b) {
    for (int e = 0; e < 8; ++e) mp[e] += probs[b * 8 + e];
    fr[top1[b]] += 1.f;
  }
  float aux = 0.f;
  for (int e = 0; e < 8; ++e) aux += (mp[e] * (1.f / 64.f)) * (fr[e] * (1.f / 64.f));
  auxout[0] = 8.f * aux;
}

// ---------------- expert GEMM1 (chunked): hid = gelu(op @ w1 + b1) ----------
// token slot (e<4):  hid[d][ht] = gelu(hT[d,:n] . tm_w1T[ht,:n])
// channel slot:      hid[n][hc] = gelu(h[n,:d]  . cm_w1T[hc,:d])
// XCD swizzle: 64 tiles of one slot are work-contiguous -> same XCD L2.
__global__ __launch_bounds__(256) void k_gemm1(const u16* __restrict__ h, const u16* __restrict__ hT,
                                               const u16* __restrict__ tmw1T, const u16* __restrict__ cmw1T,
                                               const float* __restrict__ tm_b1, const float* __restrict__ cm_b1,
                                               const int* __restrict__ ti, u16* __restrict__ hid, int slot0) {
  __shared__ u16 As[12288] __attribute__((aligned(16)));
  __shared__ u16 Bs[12288] __attribute__((aligned(16)));
  const int wrk = xcd_work();
  int tile = wrk & 63;                 // gridDim.x == 64
  int ly = wrk >> 6;                   // local slot index within pass
  int slot = slot0 + ly;
  int b = slot >> 1;
  int e = ti[slot];
  f32x4 acc[4][4]; zero_acc(acc);
  const int tid = threadIdx.x, w = tid >> 6, L = tid & 63;
  const int rb = (w & 1) * 64 + ((L >> 4) << 2), cb = (w >> 1) * 64 + (L & 15);
  u16* outp = hid + (size_t)ly * 1048576;
  if (e < 4) {                     // token mixer: M=1024(d) x N=1024(ht), K=256(n)
    int tm = tile >> 3, tn = tile & 7;
    gemm_tile(hT + (size_t)b * 262144 + (size_t)tm * 128 * 256, 256,
              tmw1T + (size_t)e * 262144 + (size_t)tn * 128 * 256, 256, 256, As, Bs, acc);
    const float* bias = tm_b1 + e * 1024 + tn * 128;
#pragma unroll
    for (int i = 0; i < 4; ++i)
#pragma unroll
      for (int j = 0; j < 4; ++j) {
        int col = cb + j * 16;
        float bv = bias[col];
#pragma unroll
        for (int r = 0; r < 4; ++r) {
          int row = tm * 128 + rb + i * 16 + r;
          outp[(size_t)row * 1024 + tn * 128 + col] = f2b(gelu_f(acc[i][j][r] + bv));
        }
      }
  } else {                         // channel mixer: M=256(n) x N=4096(hc), K=1024(d)
    int ec = e - 4;
    int tm = tile >> 5, tn = tile & 31;
    gemm_tile(h + (size_t)b * 262144 + (size_t)tm * 128 * 1024, 1024,
              cmw1T + (size_t)ec * 4194304 + (size_t)tn * 128 * 1024, 1024, 1024, As, Bs, acc);
    const float* bias = cm_b1 + ec * 4096 + tn * 128;
#pragma unroll
    for (int i = 0; i < 4; ++i)
#pragma unroll
      for (int j = 0; j < 4; ++j) {
        int col = cb + j * 16;
        float bv = bias[col];
#pragma unroll
        for (int r = 0; r < 4; ++r) {
          int row = tm * 128 + rb + i * 16 + r;
          outp[(size_t)row * 4096 + tn * 128 + col] = f2b(gelu_f(acc[i][j][r] + bv));
        }
      }
  }
}

// ---------------- expert GEMM2 + combine + residual (fused dual-slot) -------
// x1[n][d] = x + g_msa * (w0*(o0+b0) + w1*(o1+b1)); both expert types emit
// [n][d] tiles (token uses swapped operand roles).
__global__ __launch_bounds__(256) void k_gemm2(const u16* __restrict__ hid,
                                               const u16* __restrict__ tmw2T, const u16* __restrict__ cmw2T,
                                               const float* __restrict__ tm_b2, const float* __restrict__ cm_b2,
                                               const int* __restrict__ ti, const float* __restrict__ tw,
                                               const float* __restrict__ x, const float* __restrict__ modp,
                                               float* __restrict__ x1, int b0) {
  __shared__ u16 As[12288] __attribute__((aligned(16)));
  __shared__ u16 Bs[12288] __attribute__((aligned(16)));
  const int wrk = xcd_work();
  int tm = (wrk & 15) >> 3, tn = wrk & 7;   // tm over n(256), tn over d(1024)
  int ly = wrk >> 4;                        // local sample within pass
  int b = b0 + ly;
  int e0 = ti[b * 2], e1 = ti[b * 2 + 1];
  float w0 = tw[b * 2], w1v = tw[b * 2 + 1];
  f32x4 acc[4][4]; zero_acc(acc);
  const int tid = threadIdx.x, w = tid >> 6, L = tid & 63;
  const int rb = (w & 1) * 64 + ((L >> 4) << 2), cb = (w >> 1) * 64 + (L & 15);
  const u16* hid0 = hid + (size_t)(2 * ly) * 1048576;
  const u16* hid1 = hid0 + 1048576;
  // ---- slot 0
  if (e0 < 4)
    gemm_tile(tmw2T + (size_t)e0 * 262144 + (size_t)tm * 128 * 1024, 1024,
              hid0 + (size_t)tn * 128 * 1024, 1024, 1024, As, Bs, acc);
  else
    gemm_tile(hid0 + (size_t)tm * 128 * 4096, 4096,
              cmw2T + (size_t)(e0 - 4) * 4194304 + (size_t)tn * 128 * 4096, 4096, 4096, As, Bs, acc);
  float ratio = w0 / w1v;
#pragma unroll
  for (int i = 0; i < 4; ++i)
#pragma unroll
    for (int j = 0; j < 4; ++j)
#pragma unroll
      for (int r = 0; r < 4; ++r) {
        int rowg = tm * 128 + rb + i * 16 + r;
        int colg = tn * 128 + cb + j * 16;
        float bv = (e0 < 4) ? tm_b2[e0 * 256 + rowg] : cm_b2[(e0 - 4) * 1024 + colg];
        acc[i][j][r] = (acc[i][j][r] + bv) * ratio;
      }
  // ---- slot 1
  if (e1 < 4)
    gemm_tile(tmw2T + (size_t)e1 * 262144 + (size_t)tm * 128 * 1024, 1024,
              hid1 + (size_t)tn * 128 * 1024, 1024, 1024, As, Bs, acc);
  else
    gemm_tile(hid1 + (size_t)tm * 128 * 4096, 4096,
              cmw2T + (size_t)(e1 - 4) * 4194304 + (size_t)tn * 128 * 4096, 4096, 4096, As, Bs, acc);
  const float* xrow = x + (size_t)b * 262144;
  const float* gm = modp + b * 6144 + 2048;
  float* orow = x1 + (size_t)b * 262144;
#pragma unroll
  for (int i = 0; i < 4; ++i)
#pragma unroll
    for (int j = 0; j < 4; ++j)
#pragma unroll
      for (int r = 0; r < 4; ++r) {
        int rowg = tm * 128 + rb + i * 16 + r;
        int colg = tn * 128 + cb + j * 16;
        float bv = (e1 < 4) ? tm_b2[e1 * 256 + rowg] : cm_b2[(e1 - 4) * 1024 + colg];
        float val = w1v * (acc[i][j][r] + bv);
        size_t idx = (size_t)rowg * 1024 + colg;
        orow[idx] = xrow[idx] + gm[colg] * val;
      }
}

// ---------------- MLP GEMM1 (row-chunked): mhid = gelu(h2 @ w1 + b1) --------
__global__ __launch_bounds__(256) void k_mlp1(const u16* __restrict__ h2, const u16* __restrict__ w1T,
                                              const float* __restrict__ b1, u16* __restrict__ mhid, int r0) {
  __shared__ u16 As[12288] __attribute__((aligned(16)));
  __shared__ u16 Bs[12288] __attribute__((aligned(16)));
  const int wrk = xcd_work();
  int tn = wrk & 31, tm = wrk >> 5;       // gridDim.x == 32
  f32x4 acc[4][4]; zero_acc(acc);
  gemm_tile(h2 + (size_t)(r0 + tm * 128) * 1024, 1024, w1T + (size_t)tn * 131072, 1024, 1024, As, Bs, acc);
  const int tid = threadIdx.x, w = tid >> 6, L = tid & 63;
  const int rb = (w & 1) * 64 + ((L >> 4) << 2), cb = (w >> 1) * 64 + (L & 15);
  const float* bias = b1 + tn * 128;
#pragma unroll
  for (int i = 0; i < 4; ++i)
#pragma unroll
    for (int j = 0; j < 4; ++j) {
      int col = cb + j * 16;
      float bv = bias[col];
#pragma unroll
      for (int r = 0; r < 4; ++r) {
        int row = tm * 128 + rb + i * 16 + r;   // local row in chunk
        mhid[(size_t)row * 4096 + tn * 128 + col] = f2b(gelu_f(acc[i][j][r] + bv));
      }
    }
}

// ---------------- MLP GEMM2 + final residual (in-place on d_out) ------------
__global__ __launch_bounds__(256) void k_mlp2(const u16* __restrict__ mhid, const u16* __restrict__ w2T,
                                              const float* __restrict__ b2, const float* __restrict__ modp,
                                              float* __restrict__ xio, int r0) {
  __shared__ u16 As[12288] __attribute__((aligned(16)));
  __shared__ u16 Bs[12288] __attribute__((aligned(16)));
  const int wrk = xcd_work();
  int tn = wrk & 7, tm = wrk >> 3;        // gridDim.x == 8
  f32x4 acc[4][4]; zero_acc(acc);
  gemm_tile(mhid + (size_t)tm * 524288, 4096, w2T + (size_t)tn * 524288, 4096, 4096, As, Bs, acc);
  const int tid = threadIdx.x, w = tid >> 6, L = tid & 63;
  const int rb = (w & 1) * 64 + ((L >> 4) << 2), cb = (w >> 1) * 64 + (L & 15);
#pragma unroll
  for (int i = 0; i < 4; ++i)
#pragma unroll
    for (int j = 0; j < 4; ++j) {
      int col = tn * 128 + cb + j * 16;
      float bv = b2[col];
#pragma unroll
      for (int r = 0; r < 4; ++r) {
        int gr = r0 + tm * 128 + rb + i * 16 + r;   // global flat row [0,16384)
        int bq = gr >> 8;
        size_t idx = (size_t)gr * 1024 + col;
        xio[idx] = xio[idx] + modp[bq * 6144 + 5120 + col] * (acc[i][j][r] + bv);
      }
    }
}

// ---------------- host ------------------------------------------------------
extern "C" void kernel_launch(void* const* d_in, const int* in_sizes, int n_in,
                              void* d_out, int out_size, void* d_ws, size_t ws_size,
                              hipStream_t stream) {
  (void)in_sizes; (void)n_in; (void)out_size;
  const float* x        = (const float*)d_in[0];
  const float* c        = (const float*)d_in[1];
  const float* w_ada    = (const float*)d_in[2];
  const float* b_ada    = (const float*)d_in[3];
  const float* w_router = (const float*)d_in[4];
  const float* tm_w1    = (const float*)d_in[5];
  const float* tm_b1    = (const float*)d_in[6];
  const float* tm_w2    = (const float*)d_in[7];
  const float* tm_b2    = (const float*)d_in[8];
  const float* cm_w1    = (const float*)d_in[9];
  const float* cm_b1    = (const float*)d_in[10];
  const float* cm_w2    = (const float*)d_in[11];
  const float* cm_b2    = (const float*)d_in[12];
  const float* mlp_w1   = (const float*)d_in[13];
  const float* mlp_b1   = (const float*)d_in[14];
  const float* mlp_w2   = (const float*)d_in[15];
  const float* mlp_b2   = (const float*)d_in[16];

  // ---- fixed layout (element offsets for bf16 region) ----
  u16* ws16 = (u16*)d_ws;
  char* wsb = (char*)d_ws;
  u16* tmw1T = ws16;                       // 1,048,576 elts
  u16* tmw2T = ws16 + 1048576L;            // 1,048,576
  u16* cmw1T = ws16 + 2097152L;            // 16,777,216
  u16* cmw2T = ws16 + 18874368L;           // 16,777,216
  u16* csilu = ws16 + 35651584L;           // 131,072
  u16* h     = ws16 + 35782656L;           // 16,777,216 (reused as h2)
  u16* hT    = ws16 + 52559872L;           // 16,777,216 (reused: mlp w1T/w2T)
  u16* mw1T  = ws16 + 52559872L;           // 4,194,304 (after MoE)
  u16* mw2T  = ws16 + 56754176L;           // 4,194,304
  float* modp  = (float*)(wsb + 138674176L);   // 128 x 6144 fp32
  float* rin   = (float*)(wsb + 141819904L);   // 64 x 1024
  float* probs = (float*)(wsb + 142082048L);   // 64 x 8
  float* twp   = (float*)(wsb + 142084096L);   // 128
  int*   tip   = (int*)(wsb + 142084608L);     // 128
  int*   top1p = (int*)(wsb + 142085120L);     // 64
  float* lns   = (float*)(wsb + 142085376L);   // 2 x 16384
  const size_t FIXED_END = 142216448ULL;       // tail start (16B aligned)
  u16* tailb = ws16 + FIXED_END / 2;           // adaT, then hid/mhid chunks
  float* x1 = (float*)d_out;                   // x1 lives in the output buffer

  if (ws_size < FIXED_END + 12582912ULL) {     // can't even fit adaT
    k_diag<<<1, 64, 0, stream>>>((float*)d_out, (float)(ws_size >> 20));
    return;
  }
  size_t tail = ws_size - FIXED_END;
  int C = 64;                                  // samples per MoE pass
  while ((size_t)C * 4194304ULL > tail) C >>= 1;
  int R = 16384;                               // rows per MLP pass
  while ((size_t)R * 8192ULL > tail) R >>= 1;

  // ---- T1: adaT (tail) + MoE weights ----
  TArgs t1; int k = 0, start = 0;
#define ADD_T(TA, SRC, DST, RR, CC)                                       \
  do {                                                                    \
    TA.d[k].src = (SRC); TA.d[k].dstOff = (DST);                          \
    TA.d[k].R = (RR); TA.d[k].C = (CC);                                   \
    TA.d[k].tileStart = start; TA.d[k].tilesX = (CC) / 32;                \
    start += ((RR) / 32) * ((CC) / 32); ++k;                              \
  } while (0)
  ADD_T(t1, w_ada, (long)(FIXED_END / 2), 1024, 6144);
  for (int e = 0; e < 4; ++e) ADD_T(t1, tm_w1 + (long)e * 262144, 0L + (long)e * 262144, 256, 1024);
  for (int e = 0; e < 4; ++e) ADD_T(t1, tm_w2 + (long)e * 262144, 1048576L + (long)e * 262144, 1024, 256);
  for (int e = 0; e < 4; ++e) ADD_T(t1, cm_w1 + (long)e * 4194304, 2097152L + (long)e * 4194304, 1024, 4096);
  for (int e = 0; e < 4; ++e) ADD_T(t1, cm_w2 + (long)e * 4194304, 18874368L + (long)e * 4194304, 4096, 1024);
  t1.n = k;
  int t1_tiles = start;                        // 40960

  TArgs t2; k = 0; start = 0;
  ADD_T(t2, mlp_w1, 52559872L, 1024, 4096);
  ADD_T(t2, mlp_w2, 56754176L, 4096, 1024);
  t2.n = k;
  int t2_tiles = start;                        // 8192
#undef ADD_T

  k_transpose<<<dim3(t1_tiles), dim3(256), 0, stream>>>(t1, ws16);
  k_silu<<<dim3(128), dim3(256), 0, stream>>>(c, csilu);
  k_ada<<<dim3(48), dim3(256), 0, stream>>>(csilu, tailb, b_ada, modp);
  k_ln<<<dim3(256, 64), dim3(256), 0, stream>>>(x, modp, h, lns, 0, 1024);
  k_htrans<<<dim3(32, 8, 64), dim3(256), 0, stream>>>(h, hT);
  k_rin<<<dim3(4, 64), dim3(256), 0, stream>>>(x, lns, modp, rin);
  k_router<<<dim3(64), dim3(256), 0, stream>>>(rin, w_router, probs, twp, tip, top1p);
  k_aux<<<dim3(1), dim3(64), 0, stream>>>(probs, top1p, (float*)d_out + 16777216L);
  // ---- MoE passes (hid chunk in tail; overwrites adaT, which is now dead)
  for (int b0 = 0; b0 < 64; b0 += C) {
    k_gemm1<<<dim3(64, 2 * C), dim3(256), 0, stream>>>(h, hT, tmw1T, cmw1T, tm_b1, cm_b1, tip, tailb, 2 * b0);
    k_gemm2<<<dim3(16, C), dim3(256), 0, stream>>>(tailb, tmw2T, cmw2T, tm_b2, cm_b2, tip, twp, x, modp, x1, b0);
  }
  // ---- MLP weights into hT region (dead after last k_gemm1) ----
  k_transpose<<<dim3(t2_tiles), dim3(256), 0, stream>>>(t2, ws16);
  k_ln<<<dim3(256, 64), dim3(256), 0, stream>>>(x1, modp, h, nullptr, 3072, 4096);
  for (int r0 = 0; r0 < 16384; r0 += R) {
    k_mlp1<<<dim3(32, R / 128), dim3(256), 0, stream>>>(h, mw1T, mlp_b1, tailb, r0);
    k_mlp2<<<dim3(8, R / 128), dim3(256), 0, stream>>>(tailb, mw2T, mlp_b2, modp, x1, r0);
  }
}